// Round 6
// baseline (23660.146 us; speedup 1.0000x reference)
//
#include <hip/hip_runtime.h>
#include <hip/hip_bf16.h>

// NeuralODE Bosh3 fixed-step integrator, persistent-block formulation.
// Round 6: BT=64 (32 blocks x 512 thr, 8 waves). Each wave computes a 64x64
// output tile per layer (4 nt x 4 M-panels) so every weight fragment is
// loaded from global exactly ONCE per block-eval (4x demand reduction).
// Weights repacked so each wave's fragment stream is contiguous.
// LDS: x 24 KB + h1 64 KB + h2 64 KB = 152 KB, 1 block/CU.

#define B_ 2048
#define L_ 128
#define P_ 8
#define W_ 512
#define T_ 128
#define BT_ 64
#define NBLK (B_/BT_)          // 32 blocks

typedef __attribute__((ext_vector_type(8))) short short8;
typedef __attribute__((ext_vector_type(4))) float f32x4;

// packed weight sizes (ushort elements); fragment = 64 lanes x 8 = 512
#define W0P_ELEMS (8*5*4*512)    // [g8][kt5][ntl4] fragments (Kpad=160)
#define W1P_ELEMS (8*16*4*512)   // [g8][kt16][ntl4]
#define W2P_ELEMS (8*16*512)     // [nt8][kt16]
#define W1P_OFF (W0P_ELEMS)
#define W2P_OFF (W0P_ELEMS + W1P_ELEMS)
#define WTOT (W0P_ELEMS + W1P_ELEMS + W2P_ELEMS)   // 409600 ushorts

__device__ __forceinline__ unsigned short f2bf(float f){
  unsigned u = __builtin_bit_cast(unsigned, f);
  u += 0x7fffu + ((u >> 16) & 1u);          // round-to-nearest-even
  return (unsigned short)(u >> 16);
}

__device__ __forceinline__ float tanh_fast(float x){
  float e = __expf(2.0f * x);
  return 1.0f - __fdividef(2.0f, e + 1.0f); // exact at saturation (+-1)
}

// Pack W[n][k] (row-major fp32) into per-wave-contiguous MFMA B-fragments.
// L1/L2: frag(g,kt,ntl): nt=4g+ntl, elem ((g*KT+kt)*4+ntl)*512 + lane*8 + j
//        holds bf16(W[nt*16+(lane&15)][kt*32+(lane>>4)*8+j]).
// L3:    frag(nt,kt) at (nt*16+kt)*512.
// idx in [WTOT, WTOT+T_-1): dts[idx-WTOT] = ts[i+1]-ts[i] (fp32) at wp+WTOT.
__global__ void prep_weights(const float* __restrict__ W0,
                             const float* __restrict__ W1,
                             const float* __restrict__ W2,
                             const float* __restrict__ ts,
                             unsigned short* __restrict__ wp){
  int idx = blockIdx.x * blockDim.x + threadIdx.x;
  if (idx >= WTOT){
    int t = idx - WTOT;
    if (t < T_ - 1){
      float* dts = (float*)(wp + WTOT);
      dts[t] = ts[t+1] - ts[t];
    }
    return;
  }
  const float* src; int base, KT, Korig, isL3;
  if (idx < W1P_OFF)      { src = W0; base = 0;       KT = 5;  Korig = 136; isL3 = 0; }
  else if (idx < W2P_OFF) { src = W1; base = W1P_OFF; KT = 16; Korig = 512; isL3 = 0; }
  else                    { src = W2; base = W2P_OFF; KT = 16; Korig = 512; isL3 = 1; }
  int e    = idx - base;
  int j    = e & 7;
  int lane = (e >> 3) & 63;
  int tile = e >> 9;
  int nt, kt;
  if (isL3){ kt = tile & 15; nt = tile >> 4; }
  else     { int ntl = tile & 3; int ktg = tile >> 2; kt = ktg % KT; nt = (ktg / KT)*4 + ntl; }
  int row  = nt*16 + (lane & 15);
  int k    = kt*32 + ((lane >> 4) << 3) + j;
  float v  = (k < Korig) ? src[row*Korig + k] : 0.0f;
  wp[idx] = f2bf(v);
}

// LDS layouts (bf16, XOR-swizzled: byte ^= (rowkey&7)<<4; row strides are
// multiples of 128B so the swizzle stays within the row -> bijective).
#define XROWB 384    // x: 192 ushorts/row (0..127 y, 128..135 args, rest 0)
#define HROWB 1024   // h: 512 ushorts/row

__global__ __launch_bounds__(512, 2)
void ode_main(const float* __restrict__ x0,
              const float* __restrict__ args,
              const float* __restrict__ b0, const float* __restrict__ b1,
              const float* __restrict__ b2,
              const unsigned short* __restrict__ wp,
              float* __restrict__ out){
  __shared__ __align__(16) unsigned short xb[BT_*(XROWB/2)];   // 24 KiB
  __shared__ __align__(16) unsigned short h1[BT_*(HROWB/2)];   // 64 KiB
  __shared__ __align__(16) unsigned short h2[BT_*(HROWB/2)];   // 64 KiB

  const int tid  = threadIdx.x;
  const int lane = tid & 63;
  const int wv   = tid >> 6;     // wave 0..7
  const int lo   = lane & 15;
  const int hi   = lane >> 4;    // 0..3
  const int r0   = blockIdx.x * BT_;

  const unsigned short* w0p = wp;
  const unsigned short* w1p = wp + W1P_OFF;
  const unsigned short* w2p = wp + W2P_OFF;
  const float* dts = (const float*)(wp + WTOT);

  // zero x buffer (zeroes are swizzle-invariant)
  for (int i = tid; i < BT_*(XROWB/2); i += 512) xb[i] = 0;
  __syncthreads();

  // args -> x cols 128..135 (constant across all steps)
  {
    int r = tid >> 3, pp = tid & 7;           // 512 threads = 64 rows x 8
    unsigned short v = f2bf(args[(r0 + r)*P_ + pp]);
    *(unsigned short*)((char*)xb + r*XROWB + (((128 + pp)*2) ^ ((r & 7) << 4))) = v;
  }

  const int aswz = (lo & 7) << 4;

  // biases: wave owns nt = 4wv+n (layers 1/2), col block wv (layer 3)
  float b0v[4], b1v[4];
  #pragma unroll
  for (int n = 0; n < 4; ++n){
    b0v[n] = b0[(4*wv + n)*16 + lo];
    b1v[n] = b1[(4*wv + n)*16 + lo];
  }
  const int c3 = wv*16 + lo;
  float b2v = b2[c3];

  // ODE state: rows p*16+4hi+j (p=0..3), col c3
  float yr[4][4], yn[4][4];
  #pragma unroll
  for (int p = 0; p < 4; ++p)
    #pragma unroll
    for (int j = 0; j < 4; ++j){
      int row = p*16 + 4*hi + j;
      float v = x0[(r0 + row)*L_ + c3];
      yr[p][j] = v;
      __builtin_nontemporal_store(v, &out[((r0 + row)*T_ + 0)*L_ + c3]);
      *(unsigned short*)((char*)xb + row*XROWB + ((c3*2) ^ ((row & 7) << 4))) = f2bf(v);
    }

  // One vector-field eval: x(LDS) -> h1 -> h2 -> d[p] (layer-3 acc, no bias)
  auto evalf = [&](f32x4 (&dout)[4]){
    f32x4 acc[4][4];   // [n][p]
    // ---- layer 1: K=160 (5 kt); 64x64 tile: nt=4wv+n, panels p
    #pragma unroll
    for (int n = 0; n < 4; ++n)
      #pragma unroll
      for (int p = 0; p < 4; ++p) acc[n][p] = f32x4{0.f,0.f,0.f,0.f};
    #pragma unroll
    for (int kt = 0; kt < 5; ++kt){
      short8 a[4], bq[4];
      #pragma unroll
      for (int p = 0; p < 4; ++p)
        a[p] = *(const short8*)((const char*)xb + (p*16+lo)*XROWB + ((kt*64 + hi*16) ^ aswz));
      #pragma unroll
      for (int n = 0; n < 4; ++n)
        bq[n] = *(const short8*)(w0p + (((wv*5 + kt)*4 + n) << 9) + lane*8);
      #pragma unroll
      for (int n = 0; n < 4; ++n)
        #pragma unroll
        for (int p = 0; p < 4; ++p)
          acc[n][p] = __builtin_amdgcn_mfma_f32_16x16x32_bf16(a[p], bq[n], acc[n][p], 0, 0, 0);
    }
    #pragma unroll
    for (int n = 0; n < 4; ++n)
      #pragma unroll
      for (int p = 0; p < 4; ++p)
        #pragma unroll
        for (int j = 0; j < 4; ++j){
          float v = tanh_fast(acc[n][p][j] + b0v[n]);
          int row = p*16 + 4*hi + j;
          int col = (4*wv + n)*16 + lo;
          *(unsigned short*)((char*)h1 + row*HROWB + ((col*2) ^ ((row & 7) << 4))) = f2bf(v);
        }
    __syncthreads();
    // ---- layer 2: K=512 (16 kt)
    #pragma unroll
    for (int n = 0; n < 4; ++n)
      #pragma unroll
      for (int p = 0; p < 4; ++p) acc[n][p] = f32x4{0.f,0.f,0.f,0.f};
    #pragma unroll
    for (int kt = 0; kt < 16; ++kt){
      short8 a[4], bq[4];
      #pragma unroll
      for (int p = 0; p < 4; ++p)
        a[p] = *(const short8*)((const char*)h1 + (p*16+lo)*HROWB + ((kt*64 + hi*16) ^ aswz));
      #pragma unroll
      for (int n = 0; n < 4; ++n)
        bq[n] = *(const short8*)(w1p + (((wv*16 + kt)*4 + n) << 9) + lane*8);
      #pragma unroll
      for (int n = 0; n < 4; ++n)
        #pragma unroll
        for (int p = 0; p < 4; ++p)
          acc[n][p] = __builtin_amdgcn_mfma_f32_16x16x32_bf16(a[p], bq[n], acc[n][p], 0, 0, 0);
    }
    #pragma unroll
    for (int n = 0; n < 4; ++n)
      #pragma unroll
      for (int p = 0; p < 4; ++p)
        #pragma unroll
        for (int j = 0; j < 4; ++j){
          float v = tanh_fast(acc[n][p][j] + b1v[n]);
          int row = p*16 + 4*hi + j;
          int col = (4*wv + n)*16 + lo;
          *(unsigned short*)((char*)h2 + row*HROWB + ((col*2) ^ ((row & 7) << 4))) = f2bf(v);
        }
    __syncthreads();
    // ---- layer 3: K=512 (16 kt), N=128; wave wv owns col block wv, 4 panels
    f32x4 a3[4];
    #pragma unroll
    for (int p = 0; p < 4; ++p) a3[p] = f32x4{0.f,0.f,0.f,0.f};
    #pragma unroll
    for (int kt = 0; kt < 16; ++kt){
      short8 a[4];
      #pragma unroll
      for (int p = 0; p < 4; ++p)
        a[p] = *(const short8*)((const char*)h2 + (p*16+lo)*HROWB + ((kt*64 + hi*16) ^ aswz));
      short8 bq = *(const short8*)(w2p + ((wv*16 + kt) << 9) + lane*8);
      #pragma unroll
      for (int p = 0; p < 4; ++p)
        a3[p] = __builtin_amdgcn_mfma_f32_16x16x32_bf16(a[p], bq, a3[p], 0, 0, 0);
    }
    #pragma unroll
    for (int p = 0; p < 4; ++p) dout[p] = a3[p];
  };

  // Bosh3: k1=f(y); k2=f(y+dt/2 k1); k3=f(y+3dt/4 k2); y+=dt(2/9 k1+1/3 k2+4/9 k3)
  for (int t = 1; t < T_; ++t){
    float dt = dts[t-1];
    f32x4 d[4];

    __syncthreads();                       // xb ready
    evalf(d);                              // k1
    #pragma unroll
    for (int p = 0; p < 4; ++p)
      #pragma unroll
      for (int j = 0; j < 4; ++j){
        float k = d[p][j] + b2v;
        yn[p][j] = yr[p][j] + dt*(2.0f/9.0f)*k;
        float xs = yr[p][j] + 0.5f*dt*k;
        int row = p*16 + 4*hi + j;
        *(unsigned short*)((char*)xb + row*XROWB + ((c3*2) ^ ((row & 7) << 4))) = f2bf(xs);
      }

    __syncthreads();
    evalf(d);                              // k2
    #pragma unroll
    for (int p = 0; p < 4; ++p)
      #pragma unroll
      for (int j = 0; j < 4; ++j){
        float k = d[p][j] + b2v;
        yn[p][j] += dt*(1.0f/3.0f)*k;
        float xs = yr[p][j] + 0.75f*dt*k;
        int row = p*16 + 4*hi + j;
        *(unsigned short*)((char*)xb + row*XROWB + ((c3*2) ^ ((row & 7) << 4))) = f2bf(xs);
      }

    __syncthreads();
    evalf(d);                              // k3
    #pragma unroll
    for (int p = 0; p < 4; ++p)
      #pragma unroll
      for (int j = 0; j < 4; ++j){
        float k = d[p][j] + b2v;
        yn[p][j] += dt*(4.0f/9.0f)*k;
        yr[p][j] = yn[p][j];
        int row = p*16 + 4*hi + j;
        __builtin_nontemporal_store(yr[p][j], &out[((r0 + row)*T_ + t)*L_ + c3]);
        *(unsigned short*)((char*)xb + row*XROWB + ((c3*2) ^ ((row & 7) << 4))) = f2bf(yr[p][j]);
      }
  }
}

extern "C" void kernel_launch(void* const* d_in, const int* in_sizes, int n_in,
                              void* d_out, int out_size, void* d_ws, size_t ws_size,
                              hipStream_t stream) {
  const float* x0   = (const float*)d_in[0];
  const float* ts   = (const float*)d_in[1];
  const float* args = (const float*)d_in[2];
  const float* W0   = (const float*)d_in[3];
  const float* b0   = (const float*)d_in[4];
  const float* W1   = (const float*)d_in[5];
  const float* b1   = (const float*)d_in[6];
  const float* W2   = (const float*)d_in[7];
  const float* b2   = (const float*)d_in[8];
  unsigned short* wp = (unsigned short*)d_ws;   // 819,200 B weights + 512 B dts
  float* out = (float*)d_out;

  prep_weights<<<(WTOT + T_ + 255)/256, 256, 0, stream>>>(W0, W1, W2, ts, wp);
  ode_main<<<NBLK, 512, 0, stream>>>(x0, args, b0, b1, b2, wp, out);
}

// Round 7
// 13036.250 us; speedup vs baseline: 1.8150x; 1.8150x over previous
//
#include <hip/hip_runtime.h>
#include <hip/hip_bf16.h>

// NeuralODE Bosh3 fixed-step integrator, persistent-block formulation.
// Round 7: BT=32, 64 blocks x 1024 threads (16 waves, 4 waves/SIMD).
// Per wave: 2 nt x 2 panels (acc[2][2] in AGPRs), distance-1 register
// prefetch of per-wave-contiguous weight fragments, zero spill by design
// (launch_bounds(1024,4) -> 128-VGPR cap, ~70 live). Layer 3 + ODE state
// in waves 0..7. Output staged fp32 in LDS, stored as full 128B lines.

#define B_ 2048
#define L_ 128
#define P_ 8
#define W_ 512
#define T_ 128
#define BT_ 32
#define NBLK (B_/BT_)          // 64 blocks

typedef __attribute__((ext_vector_type(8))) short short8;
typedef __attribute__((ext_vector_type(4))) float f32x4;

// packed weight sizes (ushort elements); fragment = 64 lanes x 8 = 512
#define W0P_ELEMS (16*5*2*512)   // [wv16][kt5][n2] fragments (Kpad=160)
#define W1P_ELEMS (16*16*2*512)  // [wv16][kt16][n2]
#define W2P_ELEMS (8*16*512)     // [nt8][kt16]
#define W1P_OFF (W0P_ELEMS)
#define W2P_OFF (W0P_ELEMS + W1P_ELEMS)
#define WTOT (W0P_ELEMS + W1P_ELEMS + W2P_ELEMS)   // 409600 ushorts

__device__ __forceinline__ unsigned short f2bf(float f){
  unsigned u = __builtin_bit_cast(unsigned, f);
  u += 0x7fffu + ((u >> 16) & 1u);          // round-to-nearest-even
  return (unsigned short)(u >> 16);
}

__device__ __forceinline__ float tanh_fast(float x){
  float e = __expf(2.0f * x);
  return 1.0f - __fdividef(2.0f, e + 1.0f); // exact at saturation (+-1)
}

// Pack W[n][k] (row-major fp32) into per-wave-contiguous MFMA B-fragments.
// L1/L2: tile index (wv*KT + kt)*2 + n -> nt = 2*wv + n; elem tile*512 +
//        lane*8 + j holds bf16(W[nt*16+(lane&15)][kt*32+(lane>>4)*8+j]).
// L3:    tile = nt*16 + kt.
// idx in [WTOT, WTOT+T_-1): dts[idx-WTOT] = ts[i+1]-ts[i] (fp32) at wp+WTOT.
__global__ void prep_weights(const float* __restrict__ W0,
                             const float* __restrict__ W1,
                             const float* __restrict__ W2,
                             const float* __restrict__ ts,
                             unsigned short* __restrict__ wp){
  int idx = blockIdx.x * blockDim.x + threadIdx.x;
  if (idx >= WTOT){
    int t = idx - WTOT;
    if (t < T_ - 1){
      float* dts = (float*)(wp + WTOT);
      dts[t] = ts[t+1] - ts[t];
    }
    return;
  }
  const float* src; int base, KT, Korig, isL3;
  if (idx < W1P_OFF)      { src = W0; base = 0;       KT = 5;  Korig = 136; isL3 = 0; }
  else if (idx < W2P_OFF) { src = W1; base = W1P_OFF; KT = 16; Korig = 512; isL3 = 0; }
  else                    { src = W2; base = W2P_OFF; KT = 16; Korig = 512; isL3 = 1; }
  int e    = idx - base;
  int j    = e & 7;
  int lane = (e >> 3) & 63;
  int tile = e >> 9;
  int nt, kt;
  if (isL3){ kt = tile & 15; nt = tile >> 4; }
  else     { int n = tile & 1; int r2 = tile >> 1; kt = r2 % KT; nt = 2*(r2 / KT) + n; }
  int row  = nt*16 + (lane & 15);
  int k    = kt*32 + ((lane >> 4) << 3) + j;
  float v  = (k < Korig) ? src[row*Korig + k] : 0.0f;
  wp[idx] = f2bf(v);
}

// LDS layouts (bf16, XOR-swizzled: byte ^= (row&7)<<4 within the row;
// row strides are multiples of 128B so the swizzle is bijective).
#define XROWB 384    // x: 192 ushorts/row (0..127 y, 128..135 args, rest 0)
#define HROWB 1024   // h: 512 ushorts/row

__global__ __launch_bounds__(1024, 4)
void ode_main(const float* __restrict__ x0,
              const float* __restrict__ args,
              const float* __restrict__ b0, const float* __restrict__ b1,
              const float* __restrict__ b2,
              const unsigned short* __restrict__ wp,
              float* __restrict__ out){
  __shared__ __align__(16) unsigned short xb[BT_*(XROWB/2)];   // 12 KiB
  __shared__ __align__(16) unsigned short h1[BT_*(HROWB/2)];   // 32 KiB
  __shared__ __align__(16) unsigned short h2[BT_*(HROWB/2)];   // 32 KiB
  __shared__ __align__(16) float ybuf[BT_][L_];                // 16 KiB

  const int tid  = threadIdx.x;
  const int lane = tid & 63;
  const int wv   = tid >> 6;     // wave 0..15
  const int lo   = lane & 15;
  const int hi   = lane >> 4;    // 0..3
  const int r0   = blockIdx.x * BT_;
  const bool owner = (wv < 8);

  const unsigned short* w0p = wp;
  const unsigned short* w1p = wp + W1P_OFF;
  const unsigned short* w2p = wp + W2P_OFF;
  const float* dts = (const float*)(wp + WTOT);

  // zero x buffer (zeroes are swizzle-invariant)
  for (int i = tid; i < BT_*(XROWB/2); i += 1024) xb[i] = 0;
  __syncthreads();

  // args -> x cols 128..135 (constant across all steps)
  if (tid < BT_*P_){
    int r = tid >> 3, pp = tid & 7;
    unsigned short v = f2bf(args[(r0 + r)*P_ + pp]);
    *(unsigned short*)((char*)xb + r*XROWB + (((128 + pp)*2) ^ ((r & 7) << 4))) = v;
  }

  const int aswz = (lo & 7) << 4;

  // biases: wave owns nt = 2wv+n (layers 1/2)
  float b0v[2], b1v[2];
  #pragma unroll
  for (int n = 0; n < 2; ++n){
    b0v[n] = b0[(2*wv + n)*16 + lo];
    b1v[n] = b1[(2*wv + n)*16 + lo];
  }
  const int c3 = (wv & 7)*16 + lo;
  float b2v = owner ? b2[c3] : 0.0f;

  // ODE state (owners): rows p*16+4hi+j (p=0,1), col c3
  float yr[2][4], yn[2][4];
  if (owner){
    #pragma unroll
    for (int p = 0; p < 2; ++p)
      #pragma unroll
      for (int j = 0; j < 4; ++j){
        int row = p*16 + 4*hi + j;
        float v = x0[(r0 + row)*L_ + c3];
        yr[p][j] = v;
        ybuf[row][c3] = v;
        *(unsigned short*)((char*)xb + row*XROWB + ((c3*2) ^ ((row & 7) << 4))) = f2bf(v);
      }
  }

  // One vector-field eval: x(LDS) -> h1 -> h2 -> d[p] (layer-3 acc, no bias)
  auto evalf = [&](f32x4 (&dout)[2]){
    // ---- layer 1: K=160 (5 kt); wave tile = nt {2wv,2wv+1} x panels {0,1}
    {
      f32x4 acc[2][2];
      #pragma unroll
      for (int n = 0; n < 2; ++n)
        #pragma unroll
        for (int p = 0; p < 2; ++p) acc[n][p] = f32x4{0.f,0.f,0.f,0.f};
      const unsigned short* wb = w0p + (wv*5*2)*512 + lane*8;
      short8 c0 = *(const short8*)(wb);
      short8 c1 = *(const short8*)(wb + 512);
      #pragma unroll
      for (int kt = 0; kt < 5; ++kt){
        short8 n0 = c0, n1 = c1;
        if (kt < 4){
          n0 = *(const short8*)(wb + ((kt+1)*2    )*512);
          n1 = *(const short8*)(wb + ((kt+1)*2 + 1)*512);
        }
        short8 a0 = *(const short8*)((const char*)xb + lo*XROWB        + ((kt*64 + hi*16) ^ aswz));
        short8 a1 = *(const short8*)((const char*)xb + (16+lo)*XROWB   + ((kt*64 + hi*16) ^ aswz));
        acc[0][0] = __builtin_amdgcn_mfma_f32_16x16x32_bf16(a0, c0, acc[0][0], 0, 0, 0);
        acc[0][1] = __builtin_amdgcn_mfma_f32_16x16x32_bf16(a1, c0, acc[0][1], 0, 0, 0);
        acc[1][0] = __builtin_amdgcn_mfma_f32_16x16x32_bf16(a0, c1, acc[1][0], 0, 0, 0);
        acc[1][1] = __builtin_amdgcn_mfma_f32_16x16x32_bf16(a1, c1, acc[1][1], 0, 0, 0);
        c0 = n0; c1 = n1;
      }
      #pragma unroll
      for (int n = 0; n < 2; ++n)
        #pragma unroll
        for (int p = 0; p < 2; ++p)
          #pragma unroll
          for (int j = 0; j < 4; ++j){
            float v = tanh_fast(acc[n][p][j] + b0v[n]);
            int row = p*16 + 4*hi + j;
            int col = (2*wv + n)*16 + lo;
            *(unsigned short*)((char*)h1 + row*HROWB + ((col*2) ^ ((row & 7) << 4))) = f2bf(v);
          }
    }
    __syncthreads();
    // ---- layer 2: K=512 (16 kt)
    {
      f32x4 acc[2][2];
      #pragma unroll
      for (int n = 0; n < 2; ++n)
        #pragma unroll
        for (int p = 0; p < 2; ++p) acc[n][p] = f32x4{0.f,0.f,0.f,0.f};
      const unsigned short* wb = w1p + (wv*16*2)*512 + lane*8;
      short8 c0 = *(const short8*)(wb);
      short8 c1 = *(const short8*)(wb + 512);
      #pragma unroll
      for (int kt = 0; kt < 16; ++kt){
        short8 n0 = c0, n1 = c1;
        if (kt < 15){
          n0 = *(const short8*)(wb + ((kt+1)*2    )*512);
          n1 = *(const short8*)(wb + ((kt+1)*2 + 1)*512);
        }
        short8 a0 = *(const short8*)((const char*)h1 + lo*HROWB      + ((kt*64 + hi*16) ^ aswz));
        short8 a1 = *(const short8*)((const char*)h1 + (16+lo)*HROWB + ((kt*64 + hi*16) ^ aswz));
        acc[0][0] = __builtin_amdgcn_mfma_f32_16x16x32_bf16(a0, c0, acc[0][0], 0, 0, 0);
        acc[0][1] = __builtin_amdgcn_mfma_f32_16x16x32_bf16(a1, c0, acc[0][1], 0, 0, 0);
        acc[1][0] = __builtin_amdgcn_mfma_f32_16x16x32_bf16(a0, c1, acc[1][0], 0, 0, 0);
        acc[1][1] = __builtin_amdgcn_mfma_f32_16x16x32_bf16(a1, c1, acc[1][1], 0, 0, 0);
        c0 = n0; c1 = n1;
      }
      #pragma unroll
      for (int n = 0; n < 2; ++n)
        #pragma unroll
        for (int p = 0; p < 2; ++p)
          #pragma unroll
          for (int j = 0; j < 4; ++j){
            float v = tanh_fast(acc[n][p][j] + b1v[n]);
            int row = p*16 + 4*hi + j;
            int col = (2*wv + n)*16 + lo;
            *(unsigned short*)((char*)h2 + row*HROWB + ((col*2) ^ ((row & 7) << 4))) = f2bf(v);
          }
    }
    __syncthreads();
    // ---- layer 3: K=512 (16 kt), N=128; waves 0..7 own nt=wv, both panels
    if (owner){
      const unsigned short* wb = w2p + (wv*16)*512 + lane*8;
      short8 c = *(const short8*)(wb);
      f32x4 a3[2];
      a3[0] = f32x4{0.f,0.f,0.f,0.f};
      a3[1] = f32x4{0.f,0.f,0.f,0.f};
      #pragma unroll
      for (int kt = 0; kt < 16; ++kt){
        short8 nx = c;
        if (kt < 15) nx = *(const short8*)(wb + (kt+1)*512);
        short8 a0 = *(const short8*)((const char*)h2 + lo*HROWB      + ((kt*64 + hi*16) ^ aswz));
        short8 a1 = *(const short8*)((const char*)h2 + (16+lo)*HROWB + ((kt*64 + hi*16) ^ aswz));
        a3[0] = __builtin_amdgcn_mfma_f32_16x16x32_bf16(a0, c, a3[0], 0, 0, 0);
        a3[1] = __builtin_amdgcn_mfma_f32_16x16x32_bf16(a1, c, a3[1], 0, 0, 0);
        c = nx;
      }
      dout[0] = a3[0];
      dout[1] = a3[1];
    }
  };

  // Bosh3: k1=f(y); k2=f(y+dt/2 k1); k3=f(y+3dt/4 k2); y+=dt(2/9 k1+1/3 k2+4/9 k3)
  for (int t = 1; t < T_; ++t){
    float dt = dts[t-1];
    f32x4 d[2];

    __syncthreads();                       // xb + ybuf ready
    {                                      // store y_{t-1}: 32 rows x 512 B
      int row = tid >> 5, c4 = (tid & 31) << 2;
      f32x4 v = *(const f32x4*)&ybuf[row][c4];
      __builtin_nontemporal_store(v, (f32x4*)&out[((r0 + row)*T_ + (t-1))*L_ + c4]);
    }

    evalf(d);                              // k1
    if (owner){
      #pragma unroll
      for (int p = 0; p < 2; ++p)
        #pragma unroll
        for (int j = 0; j < 4; ++j){
          float k = d[p][j] + b2v;
          yn[p][j] = yr[p][j] + dt*(2.0f/9.0f)*k;
          float xs = yr[p][j] + 0.5f*dt*k;
          int row = p*16 + 4*hi + j;
          *(unsigned short*)((char*)xb + row*XROWB + ((c3*2) ^ ((row & 7) << 4))) = f2bf(xs);
        }
    }

    __syncthreads();
    evalf(d);                              // k2
    if (owner){
      #pragma unroll
      for (int p = 0; p < 2; ++p)
        #pragma unroll
        for (int j = 0; j < 4; ++j){
          float k = d[p][j] + b2v;
          yn[p][j] += dt*(1.0f/3.0f)*k;
          float xs = yr[p][j] + 0.75f*dt*k;
          int row = p*16 + 4*hi + j;
          *(unsigned short*)((char*)xb + row*XROWB + ((c3*2) ^ ((row & 7) << 4))) = f2bf(xs);
        }
    }

    __syncthreads();
    evalf(d);                              // k3
    if (owner){
      #pragma unroll
      for (int p = 0; p < 2; ++p)
        #pragma unroll
        for (int j = 0; j < 4; ++j){
          float k = d[p][j] + b2v;
          yn[p][j] += dt*(4.0f/9.0f)*k;
          yr[p][j] = yn[p][j];
          int row = p*16 + 4*hi + j;
          ybuf[row][c3] = yr[p][j];
          *(unsigned short*)((char*)xb + row*XROWB + ((c3*2) ^ ((row & 7) << 4))) = f2bf(yr[p][j]);
        }
    }
  }

  // final slice t = T_-1
  __syncthreads();
  {
    int row = tid >> 5, c4 = (tid & 31) << 2;
    f32x4 v = *(const f32x4*)&ybuf[row][c4];
    __builtin_nontemporal_store(v, (f32x4*)&out[((r0 + row)*T_ + (T_-1))*L_ + c4]);
  }
}

extern "C" void kernel_launch(void* const* d_in, const int* in_sizes, int n_in,
                              void* d_out, int out_size, void* d_ws, size_t ws_size,
                              hipStream_t stream) {
  const float* x0   = (const float*)d_in[0];
  const float* ts   = (const float*)d_in[1];
  const float* args = (const float*)d_in[2];
  const float* W0   = (const float*)d_in[3];
  const float* b0   = (const float*)d_in[4];
  const float* W1   = (const float*)d_in[5];
  const float* b1   = (const float*)d_in[6];
  const float* W2   = (const float*)d_in[7];
  const float* b2   = (const float*)d_in[8];
  unsigned short* wp = (unsigned short*)d_ws;   // 819,200 B weights + 512 B dts
  float* out = (float*)d_out;

  prep_weights<<<(WTOT + T_ + 255)/256, 256, 0, stream>>>(W0, W1, W2, ts, wp);
  ode_main<<<NBLK, 1024, 0, stream>>>(x0, args, b0, b1, b2, wp, out);
}

// Round 8
// 13030.798 us; speedup vs baseline: 1.8157x; 1.0004x over previous
//
#include <hip/hip_runtime.h>
#include <hip/hip_bf16.h>

// NeuralODE Bosh3 fixed-step integrator, persistent-block formulation.
// Round 8: identical structure to round 7 (BT=32, 64 blocks x 1024 threads,
// 16 waves, per-wave 2nt x 2panel tiles, distance-1 weight prefetch), but
// register budget pinned via amdgpu_waves_per_eu(4,4) -> 128 VGPRs/wave.
// Rounds 2-7 all spilled (allocator capped at 64/128 regs); the multi-GB
// FETCH/WRITE was scratch traffic + weight refetch from scratch thrash.

#define B_ 2048
#define L_ 128
#define P_ 8
#define W_ 512
#define T_ 128
#define BT_ 32
#define NBLK (B_/BT_)          // 64 blocks

typedef __attribute__((ext_vector_type(8))) short short8;
typedef __attribute__((ext_vector_type(4))) float f32x4;

// packed weight sizes (ushort elements); fragment = 64 lanes x 8 = 512
#define W0P_ELEMS (16*5*2*512)   // [wv16][kt5][n2] fragments (Kpad=160)
#define W1P_ELEMS (16*16*2*512)  // [wv16][kt16][n2]
#define W2P_ELEMS (8*16*512)     // [nt8][kt16]
#define W1P_OFF (W0P_ELEMS)
#define W2P_OFF (W0P_ELEMS + W1P_ELEMS)
#define WTOT (W0P_ELEMS + W1P_ELEMS + W2P_ELEMS)   // 409600 ushorts

__device__ __forceinline__ unsigned short f2bf(float f){
  unsigned u = __builtin_bit_cast(unsigned, f);
  u += 0x7fffu + ((u >> 16) & 1u);          // round-to-nearest-even
  return (unsigned short)(u >> 16);
}

__device__ __forceinline__ float tanh_fast(float x){
  float e = __expf(2.0f * x);
  return 1.0f - __fdividef(2.0f, e + 1.0f); // exact at saturation (+-1)
}

// Pack W[n][k] (row-major fp32) into per-wave-contiguous MFMA B-fragments.
// L1/L2: tile index (wv*KT + kt)*2 + n -> nt = 2*wv + n; elem tile*512 +
//        lane*8 + j holds bf16(W[nt*16+(lane&15)][kt*32+(lane>>4)*8+j]).
// L3:    tile = nt*16 + kt.
// idx in [WTOT, WTOT+T_-1): dts[idx-WTOT] = ts[i+1]-ts[i] (fp32) at wp+WTOT.
__global__ void prep_weights(const float* __restrict__ W0,
                             const float* __restrict__ W1,
                             const float* __restrict__ W2,
                             const float* __restrict__ ts,
                             unsigned short* __restrict__ wp){
  int idx = blockIdx.x * blockDim.x + threadIdx.x;
  if (idx >= WTOT){
    int t = idx - WTOT;
    if (t < T_ - 1){
      float* dts = (float*)(wp + WTOT);
      dts[t] = ts[t+1] - ts[t];
    }
    return;
  }
  const float* src; int base, KT, Korig, isL3;
  if (idx < W1P_OFF)      { src = W0; base = 0;       KT = 5;  Korig = 136; isL3 = 0; }
  else if (idx < W2P_OFF) { src = W1; base = W1P_OFF; KT = 16; Korig = 512; isL3 = 0; }
  else                    { src = W2; base = W2P_OFF; KT = 16; Korig = 512; isL3 = 1; }
  int e    = idx - base;
  int j    = e & 7;
  int lane = (e >> 3) & 63;
  int tile = e >> 9;
  int nt, kt;
  if (isL3){ kt = tile & 15; nt = tile >> 4; }
  else     { int n = tile & 1; int r2 = tile >> 1; kt = r2 % KT; nt = 2*(r2 / KT) + n; }
  int row  = nt*16 + (lane & 15);
  int k    = kt*32 + ((lane >> 4) << 3) + j;
  float v  = (k < Korig) ? src[row*Korig + k] : 0.0f;
  wp[idx] = f2bf(v);
}

// LDS layouts (bf16, XOR-swizzled: byte ^= (row&7)<<4 within the row;
// row strides are multiples of 128B so the swizzle is bijective).
#define XROWB 384    // x: 192 ushorts/row (0..127 y, 128..135 args, rest 0)
#define HROWB 1024   // h: 512 ushorts/row

__global__ __launch_bounds__(1024)
__attribute__((amdgpu_waves_per_eu(4, 4)))
void ode_main(const float* __restrict__ x0,
              const float* __restrict__ args,
              const float* __restrict__ b0, const float* __restrict__ b1,
              const float* __restrict__ b2,
              const unsigned short* __restrict__ wp,
              float* __restrict__ out){
  __shared__ __align__(16) unsigned short xb[BT_*(XROWB/2)];   // 12 KiB
  __shared__ __align__(16) unsigned short h1[BT_*(HROWB/2)];   // 32 KiB
  __shared__ __align__(16) unsigned short h2[BT_*(HROWB/2)];   // 32 KiB
  __shared__ __align__(16) float ybuf[BT_][L_];                // 16 KiB

  const int tid  = threadIdx.x;
  const int lane = tid & 63;
  const int wv   = tid >> 6;     // wave 0..15
  const int lo   = lane & 15;
  const int hi   = lane >> 4;    // 0..3
  const int r0   = blockIdx.x * BT_;
  const bool owner = (wv < 8);

  const unsigned short* w0p = wp;
  const unsigned short* w1p = wp + W1P_OFF;
  const unsigned short* w2p = wp + W2P_OFF;
  const float* dts = (const float*)(wp + WTOT);

  // zero x buffer (zeroes are swizzle-invariant)
  for (int i = tid; i < BT_*(XROWB/2); i += 1024) xb[i] = 0;
  __syncthreads();

  // args -> x cols 128..135 (constant across all steps)
  if (tid < BT_*P_){
    int r = tid >> 3, pp = tid & 7;
    unsigned short v = f2bf(args[(r0 + r)*P_ + pp]);
    *(unsigned short*)((char*)xb + r*XROWB + (((128 + pp)*2) ^ ((r & 7) << 4))) = v;
  }

  const int aswz = (lo & 7) << 4;

  // biases: wave owns nt = 2wv+n (layers 1/2)
  float b0v[2], b1v[2];
  #pragma unroll
  for (int n = 0; n < 2; ++n){
    b0v[n] = b0[(2*wv + n)*16 + lo];
    b1v[n] = b1[(2*wv + n)*16 + lo];
  }
  const int c3 = (wv & 7)*16 + lo;
  float b2v = owner ? b2[c3] : 0.0f;

  // ODE state (owners): rows p*16+4hi+j (p=0,1), col c3
  float yr[2][4], yn[2][4];
  if (owner){
    #pragma unroll
    for (int p = 0; p < 2; ++p)
      #pragma unroll
      for (int j = 0; j < 4; ++j){
        int row = p*16 + 4*hi + j;
        float v = x0[(r0 + row)*L_ + c3];
        yr[p][j] = v;
        ybuf[row][c3] = v;          // slice t=0 stored by loop-top full-line store
        *(unsigned short*)((char*)xb + row*XROWB + ((c3*2) ^ ((row & 7) << 4))) = f2bf(v);
      }
  }

  // One vector-field eval: x(LDS) -> h1 -> h2 -> d[p] (layer-3 acc, no bias)
  auto evalf = [&](f32x4 (&dout)[2]){
    // ---- layer 1: K=160 (5 kt); wave tile = nt {2wv,2wv+1} x panels {0,1}
    {
      f32x4 acc[2][2];
      #pragma unroll
      for (int n = 0; n < 2; ++n)
        #pragma unroll
        for (int p = 0; p < 2; ++p) acc[n][p] = f32x4{0.f,0.f,0.f,0.f};
      const unsigned short* wb = w0p + (wv*5*2)*512 + lane*8;
      short8 c0 = *(const short8*)(wb);
      short8 c1 = *(const short8*)(wb + 512);
      #pragma unroll
      for (int kt = 0; kt < 5; ++kt){
        short8 n0 = c0, n1 = c1;
        if (kt < 4){
          n0 = *(const short8*)(wb + ((kt+1)*2    )*512);
          n1 = *(const short8*)(wb + ((kt+1)*2 + 1)*512);
        }
        short8 a0 = *(const short8*)((const char*)xb + lo*XROWB        + ((kt*64 + hi*16) ^ aswz));
        short8 a1 = *(const short8*)((const char*)xb + (16+lo)*XROWB   + ((kt*64 + hi*16) ^ aswz));
        acc[0][0] = __builtin_amdgcn_mfma_f32_16x16x32_bf16(a0, c0, acc[0][0], 0, 0, 0);
        acc[0][1] = __builtin_amdgcn_mfma_f32_16x16x32_bf16(a1, c0, acc[0][1], 0, 0, 0);
        acc[1][0] = __builtin_amdgcn_mfma_f32_16x16x32_bf16(a0, c1, acc[1][0], 0, 0, 0);
        acc[1][1] = __builtin_amdgcn_mfma_f32_16x16x32_bf16(a1, c1, acc[1][1], 0, 0, 0);
        c0 = n0; c1 = n1;
      }
      #pragma unroll
      for (int n = 0; n < 2; ++n)
        #pragma unroll
        for (int p = 0; p < 2; ++p)
          #pragma unroll
          for (int j = 0; j < 4; ++j){
            float v = tanh_fast(acc[n][p][j] + b0v[n]);
            int row = p*16 + 4*hi + j;
            int col = (2*wv + n)*16 + lo;
            *(unsigned short*)((char*)h1 + row*HROWB + ((col*2) ^ ((row & 7) << 4))) = f2bf(v);
          }
    }
    __syncthreads();
    // ---- layer 2: K=512 (16 kt)
    {
      f32x4 acc[2][2];
      #pragma unroll
      for (int n = 0; n < 2; ++n)
        #pragma unroll
        for (int p = 0; p < 2; ++p) acc[n][p] = f32x4{0.f,0.f,0.f,0.f};
      const unsigned short* wb = w1p + (wv*16*2)*512 + lane*8;
      short8 c0 = *(const short8*)(wb);
      short8 c1 = *(const short8*)(wb + 512);
      #pragma unroll
      for (int kt = 0; kt < 16; ++kt){
        short8 n0 = c0, n1 = c1;
        if (kt < 15){
          n0 = *(const short8*)(wb + ((kt+1)*2    )*512);
          n1 = *(const short8*)(wb + ((kt+1)*2 + 1)*512);
        }
        short8 a0 = *(const short8*)((const char*)h1 + lo*HROWB      + ((kt*64 + hi*16) ^ aswz));
        short8 a1 = *(const short8*)((const char*)h1 + (16+lo)*HROWB + ((kt*64 + hi*16) ^ aswz));
        acc[0][0] = __builtin_amdgcn_mfma_f32_16x16x32_bf16(a0, c0, acc[0][0], 0, 0, 0);
        acc[0][1] = __builtin_amdgcn_mfma_f32_16x16x32_bf16(a1, c0, acc[0][1], 0, 0, 0);
        acc[1][0] = __builtin_amdgcn_mfma_f32_16x16x32_bf16(a0, c1, acc[1][0], 0, 0, 0);
        acc[1][1] = __builtin_amdgcn_mfma_f32_16x16x32_bf16(a1, c1, acc[1][1], 0, 0, 0);
        c0 = n0; c1 = n1;
      }
      #pragma unroll
      for (int n = 0; n < 2; ++n)
        #pragma unroll
        for (int p = 0; p < 2; ++p)
          #pragma unroll
          for (int j = 0; j < 4; ++j){
            float v = tanh_fast(acc[n][p][j] + b1v[n]);
            int row = p*16 + 4*hi + j;
            int col = (2*wv + n)*16 + lo;
            *(unsigned short*)((char*)h2 + row*HROWB + ((col*2) ^ ((row & 7) << 4))) = f2bf(v);
          }
    }
    __syncthreads();
    // ---- layer 3: K=512 (16 kt), N=128; waves 0..7 own nt=wv, both panels
    if (owner){
      const unsigned short* wb = w2p + (wv*16)*512 + lane*8;
      short8 c = *(const short8*)(wb);
      f32x4 a3[2];
      a3[0] = f32x4{0.f,0.f,0.f,0.f};
      a3[1] = f32x4{0.f,0.f,0.f,0.f};
      #pragma unroll
      for (int kt = 0; kt < 16; ++kt){
        short8 nx = c;
        if (kt < 15) nx = *(const short8*)(wb + (kt+1)*512);
        short8 a0 = *(const short8*)((const char*)h2 + lo*HROWB      + ((kt*64 + hi*16) ^ aswz));
        short8 a1 = *(const short8*)((const char*)h2 + (16+lo)*HROWB + ((kt*64 + hi*16) ^ aswz));
        a3[0] = __builtin_amdgcn_mfma_f32_16x16x32_bf16(a0, c, a3[0], 0, 0, 0);
        a3[1] = __builtin_amdgcn_mfma_f32_16x16x32_bf16(a1, c, a3[1], 0, 0, 0);
        c = nx;
      }
      dout[0] = a3[0];
      dout[1] = a3[1];
    }
  };

  // Bosh3: k1=f(y); k2=f(y+dt/2 k1); k3=f(y+3dt/4 k2); y+=dt(2/9 k1+1/3 k2+4/9 k3)
  for (int t = 1; t < T_; ++t){
    float dt = dts[t-1];
    f32x4 d[2];

    __syncthreads();                       // xb + ybuf ready
    {                                      // store y_{t-1}: 32 rows x 512 B
      int row = tid >> 5, c4 = (tid & 31) << 2;
      f32x4 v = *(const f32x4*)&ybuf[row][c4];
      __builtin_nontemporal_store(v, (f32x4*)&out[((r0 + row)*T_ + (t-1))*L_ + c4]);
    }

    evalf(d);                              // k1
    if (owner){
      #pragma unroll
      for (int p = 0; p < 2; ++p)
        #pragma unroll
        for (int j = 0; j < 4; ++j){
          float k = d[p][j] + b2v;
          yn[p][j] = yr[p][j] + dt*(2.0f/9.0f)*k;
          float xs = yr[p][j] + 0.5f*dt*k;
          int row = p*16 + 4*hi + j;
          *(unsigned short*)((char*)xb + row*XROWB + ((c3*2) ^ ((row & 7) << 4))) = f2bf(xs);
        }
    }

    __syncthreads();
    evalf(d);                              // k2
    if (owner){
      #pragma unroll
      for (int p = 0; p < 2; ++p)
        #pragma unroll
        for (int j = 0; j < 4; ++j){
          float k = d[p][j] + b2v;
          yn[p][j] += dt*(1.0f/3.0f)*k;
          float xs = yr[p][j] + 0.75f*dt*k;
          int row = p*16 + 4*hi + j;
          *(unsigned short*)((char*)xb + row*XROWB + ((c3*2) ^ ((row & 7) << 4))) = f2bf(xs);
        }
    }

    __syncthreads();
    evalf(d);                              // k3
    if (owner){
      #pragma unroll
      for (int p = 0; p < 2; ++p)
        #pragma unroll
        for (int j = 0; j < 4; ++j){
          float k = d[p][j] + b2v;
          yn[p][j] += dt*(4.0f/9.0f)*k;
          yr[p][j] = yn[p][j];
          int row = p*16 + 4*hi + j;
          ybuf[row][c3] = yr[p][j];
          *(unsigned short*)((char*)xb + row*XROWB + ((c3*2) ^ ((row & 7) << 4))) = f2bf(yr[p][j]);
        }
    }
  }

  // final slice t = T_-1
  __syncthreads();
  {
    int row = tid >> 5, c4 = (tid & 31) << 2;
    f32x4 v = *(const f32x4*)&ybuf[row][c4];
    __builtin_nontemporal_store(v, (f32x4*)&out[((r0 + row)*T_ + (T_-1))*L_ + c4]);
  }
}

extern "C" void kernel_launch(void* const* d_in, const int* in_sizes, int n_in,
                              void* d_out, int out_size, void* d_ws, size_t ws_size,
                              hipStream_t stream) {
  const float* x0   = (const float*)d_in[0];
  const float* ts   = (const float*)d_in[1];
  const float* args = (const float*)d_in[2];
  const float* W0   = (const float*)d_in[3];
  const float* b0   = (const float*)d_in[4];
  const float* W1   = (const float*)d_in[5];
  const float* b1   = (const float*)d_in[6];
  const float* W2   = (const float*)d_in[7];
  const float* b2   = (const float*)d_in[8];
  unsigned short* wp = (unsigned short*)d_ws;   // 819,200 B weights + 512 B dts
  float* out = (float*)d_out;

  prep_weights<<<(WTOT + T_ + 255)/256, 256, 0, stream>>>(W0, W1, W2, ts, wp);
  ode_main<<<NBLK, 1024, 0, stream>>>(x0, args, b0, b1, b2, wp, out);
}